// Round 2
// baseline (3854.411 us; speedup 1.0000x reference)
//
#include <hip/hip_runtime.h>
#include <cstdint>
#include <cstddef>

// Problem dims (fixed by reference)
#define BB   8
#define SS   2048
#define DIN  768
#define DHID 1024

// ---------------------------------------------------------------------------
// Tiled fp32 GEMM: C[M,N] = alpha * A[M,K] @ B + bias + res, optional relu.
// BT=false: B is [K,N] row-major (NN).  BT=true: B is [N,K] row-major (NT).
// Batched via gridDim.z with element strides sA, sB, sC.
// Tile 128x128, BK=16, 256 threads, 8x8 micro-tile per thread.
// ---------------------------------------------------------------------------
template <bool BT, bool RELU>
__global__ __launch_bounds__(256, 2)
void gemm128(const float* __restrict__ A, const float* __restrict__ Bm,
             const float* __restrict__ bias, const float* __restrict__ res,
             float* __restrict__ C, int M, int N, int K, float alpha,
             long sA, long sB, long sC) {
  __shared__ float As[16][132];   // [k][m], padded: row stride 528B (16B aligned)
  __shared__ float Bs[16][132];   // [k][n]

  A  += (long)blockIdx.z * sA;
  Bm += (long)blockIdx.z * sB;
  C  += (long)blockIdx.z * sC;

  const int tid = threadIdx.x;
  const int tn = tid & 15;        // 0..15 -> col group
  const int tm = tid >> 4;        // 0..15 -> row group
  const int bn0 = blockIdx.x * 128;
  const int bm0 = blockIdx.y * 128;

  // A staging: thread loads rows (tid>>2) and (tid>>2)+64, 4 floats at col (tid&3)*4
  const int ar = tid >> 2;
  const int ac = (tid & 3) * 4;
  // B NN staging: rows (tid>>5) and +8, 4 floats at col (tid&31)*4
  const int br = tid >> 5;
  const int bc = (tid & 31) * 4;

  float acc[8][8];
#pragma unroll
  for (int i = 0; i < 8; ++i)
#pragma unroll
    for (int j = 0; j < 8; ++j) acc[i][j] = 0.f;

  for (int k0 = 0; k0 < K; k0 += 16) {
    // ---- stage A (transposed into LDS) ----
    float4 a0 = *(const float4*)(A + (long)(bm0 + ar) * K + k0 + ac);
    float4 a1 = *(const float4*)(A + (long)(bm0 + ar + 64) * K + k0 + ac);
    As[ac + 0][ar] = a0.x; As[ac + 1][ar] = a0.y;
    As[ac + 2][ar] = a0.z; As[ac + 3][ar] = a0.w;
    As[ac + 0][ar + 64] = a1.x; As[ac + 1][ar + 64] = a1.y;
    As[ac + 2][ar + 64] = a1.z; As[ac + 3][ar + 64] = a1.w;

    // ---- stage B ----
    if (BT) {
      // B is [N,K]: load along K, scatter transposed (same pattern as A)
      float4 b0 = *(const float4*)(Bm + (long)(bn0 + ar) * K + k0 + ac);
      float4 b1 = *(const float4*)(Bm + (long)(bn0 + ar + 64) * K + k0 + ac);
      Bs[ac + 0][ar] = b0.x; Bs[ac + 1][ar] = b0.y;
      Bs[ac + 2][ar] = b0.z; Bs[ac + 3][ar] = b0.w;
      Bs[ac + 0][ar + 64] = b1.x; Bs[ac + 1][ar + 64] = b1.y;
      Bs[ac + 2][ar + 64] = b1.z; Bs[ac + 3][ar + 64] = b1.w;
    } else {
      // B is [K,N]: vector copy straight in
      float4 b0 = *(const float4*)(Bm + (long)(k0 + br) * N + bn0 + bc);
      float4 b1 = *(const float4*)(Bm + (long)(k0 + br + 8) * N + bn0 + bc);
      *(float4*)&Bs[br][bc]     = b0;
      *(float4*)&Bs[br + 8][bc] = b1;
    }
    __syncthreads();

    // ---- compute ----
#pragma unroll
    for (int kk = 0; kk < 16; ++kk) {
      float a[8], b[8];
      *(float4*)&a[0] = *(const float4*)&As[kk][tm * 8];
      *(float4*)&a[4] = *(const float4*)&As[kk][tm * 8 + 4];
      *(float4*)&b[0] = *(const float4*)&Bs[kk][tn * 8];
      *(float4*)&b[4] = *(const float4*)&Bs[kk][tn * 8 + 4];
#pragma unroll
      for (int i = 0; i < 8; ++i)
#pragma unroll
        for (int j = 0; j < 8; ++j) acc[i][j] = fmaf(a[i], b[j], acc[i][j]);
    }
    __syncthreads();
  }

  // ---- epilogue: alpha, bias, residual, relu ----
#pragma unroll
  for (int i = 0; i < 8; ++i) {
    const long row = bm0 + tm * 8 + i;
#pragma unroll
    for (int j = 0; j < 8; j += 4) {
      const int col = bn0 + tn * 8 + j;
      float4 o;
      o.x = acc[i][j + 0] * alpha;
      o.y = acc[i][j + 1] * alpha;
      o.z = acc[i][j + 2] * alpha;
      o.w = acc[i][j + 3] * alpha;
      if (bias) {
        o.x += bias[col + 0]; o.y += bias[col + 1];
        o.z += bias[col + 2]; o.w += bias[col + 3];
      }
      if (res) {
        const float4 r4 = *(const float4*)(res + row * N + col);
        o.x += r4.x; o.y += r4.y; o.z += r4.z; o.w += r4.w;
      }
      if (RELU) {
        o.x = fmaxf(o.x, 0.f); o.y = fmaxf(o.y, 0.f);
        o.z = fmaxf(o.z, 0.f); o.w = fmaxf(o.w, 0.f);
      }
      *(float4*)(C + row * N + col) = o;
    }
  }
}

// ---------------------------------------------------------------------------
// Row softmax over 2048-wide rows, one block per row, values held in regs.
// ---------------------------------------------------------------------------
__device__ inline float waveReduce(float v, bool isMax) {
#pragma unroll
  for (int off = 32; off > 0; off >>= 1) {
    float o = __shfl_xor(v, off);
    v = isMax ? fmaxf(v, o) : (v + o);
  }
  return v;
}

__global__ __launch_bounds__(256)
void softmax2048(float* __restrict__ sc) {
  __shared__ float red[4];
  float* row = sc + (size_t)blockIdx.x * 2048;
  const int tid = threadIdx.x;
  const int wave = tid >> 6, lane = tid & 63;

  float4 v0 = ((const float4*)row)[tid];
  float4 v1 = ((const float4*)row)[tid + 256];

  float mx = fmaxf(fmaxf(fmaxf(v0.x, v0.y), fmaxf(v0.z, v0.w)),
                   fmaxf(fmaxf(v1.x, v1.y), fmaxf(v1.z, v1.w)));
  mx = waveReduce(mx, true);
  if (lane == 0) red[wave] = mx;
  __syncthreads();
  mx = fmaxf(fmaxf(red[0], red[1]), fmaxf(red[2], red[3]));
  __syncthreads();

  v0.x = expf(v0.x - mx); v0.y = expf(v0.y - mx);
  v0.z = expf(v0.z - mx); v0.w = expf(v0.w - mx);
  v1.x = expf(v1.x - mx); v1.y = expf(v1.y - mx);
  v1.z = expf(v1.z - mx); v1.w = expf(v1.w - mx);

  float s = v0.x + v0.y + v0.z + v0.w + v1.x + v1.y + v1.z + v1.w;
  s = waveReduce(s, false);
  if (lane == 0) red[wave] = s;
  __syncthreads();
  s = red[0] + red[1] + red[2] + red[3];
  const float inv = 1.f / s;

  v0.x *= inv; v0.y *= inv; v0.z *= inv; v0.w *= inv;
  v1.x *= inv; v1.y *= inv; v1.z *= inv; v1.w *= inv;
  ((float4*)row)[tid] = v0;
  ((float4*)row)[tid + 256] = v1;
}

// ---------------------------------------------------------------------------
extern "C" void kernel_launch(void* const* d_in, const int* in_sizes, int n_in,
                              void* d_out, int out_size, void* d_ws, size_t ws_size,
                              hipStream_t stream) {
  const float* x  = (const float*)d_in[0];
  const float* W1 = (const float*)d_in[1];
  const float* b1 = (const float*)d_in[2];
  const float* Wq = (const float*)d_in[3];
  const float* bq = (const float*)d_in[4];
  const float* Wk = (const float*)d_in[5];
  const float* bk = (const float*)d_in[6];
  const float* Wv = (const float*)d_in[7];
  const float* bv = (const float*)d_in[8];
  const float* W2 = (const float*)d_in[9];
  const float* b2 = (const float*)d_in[10];
  const float* Ws = (const float*)d_in[11];
  const float* bs = (const float*)d_in[12];
  float* out = (float*)d_out;

  const long M  = (long)BB * SS;          // 16384
  const long MD = M * DHID;               // 16.77M elements (67 MB fp32)
  const long SD = (long)SS * DHID;        // per-batch q/k/v stride
  const long SSq = (long)SS * SS;         // per-batch score elements

  // Buffer plan:
  //   h, q, k  -> workspace (3 * MD floats)
  //   v        -> d_out (dead before final GEMM writes out; d_out re-poisoned
  //               each launch so no state carried)
  //   scores   -> workspace after k, chunked by batch to fit ws_size
  //   attn_out -> overwrites h;  residual r -> overwrites q
  float* h      = (float*)d_ws;
  float* q      = h + MD;
  float* k      = q + MD;
  float* v      = out;                    // M*DHID == out_size
  float* scores = k + MD;

  long ws_floats = (long)(ws_size / 4);
  long rem = ws_floats - 3 * MD;
  int nb = (int)(rem / SSq);
  if (nb > BB) nb = BB;
  if (nb < 1) nb = 1;  // minimum requirement: 3*MD + SS*SS floats (~218 MB)

  const float scale = 0.03125f;  // 1/sqrt(1024)

  // 1) h = relu(x @ W1 + b1)                [M, DIN] x [DIN, DHID]
  gemm128<false, true><<<dim3(DHID / 128, M / 128, 1), 256, 0, stream>>>(
      x, W1, b1, nullptr, h, M, DHID, DIN, 1.f, 0, 0, 0);

  // 2) q/k/v = h @ W* + b*                  [M, DHID] x [DHID, DHID]
  gemm128<false, false><<<dim3(DHID / 128, M / 128, 1), 256, 0, stream>>>(
      h, Wq, bq, nullptr, q, M, DHID, DHID, 1.f, 0, 0, 0);
  gemm128<false, false><<<dim3(DHID / 128, M / 128, 1), 256, 0, stream>>>(
      h, Wk, bk, nullptr, k, M, DHID, DHID, 1.f, 0, 0, 0);
  gemm128<false, false><<<dim3(DHID / 128, M / 128, 1), 256, 0, stream>>>(
      h, Wv, bv, nullptr, v, M, DHID, DHID, 1.f, 0, 0, 0);

  // 3-5) per-batch-chunk attention; attn output overwrites h (dead after QKV)
  for (int b0 = 0; b0 < BB; b0 += nb) {
    const int cb = (b0 + nb <= BB) ? nb : (BB - b0);
    // scores = scale * q_b @ k_b^T          [S, DHID] x [S, DHID]^T
    gemm128<true, false><<<dim3(SS / 128, SS / 128, cb), 256, 0, stream>>>(
        q + (long)b0 * SD, k + (long)b0 * SD, nullptr, nullptr, scores,
        SS, SS, DHID, scale, SD, SD, SSq);
    // softmax rows
    softmax2048<<<cb * SS, 256, 0, stream>>>(scores);
    // attn_out = scores @ v_b               [S, S] x [S, DHID]
    gemm128<false, false><<<dim3(DHID / 128, SS / 128, cb), 256, 0, stream>>>(
        scores, v + (long)b0 * SD, nullptr, nullptr, h + (long)b0 * SD,
        SS, DHID, SS, 1.f, SSq, SD, SD);
  }

  // 6) r = x @ Ws + bs + attn_out  -> reuse q buffer (dead after scores)
  gemm128<false, false><<<dim3(DHID / 128, M / 128, 1), 256, 0, stream>>>(
      x, Ws, bs, h, q, M, DHID, DIN, 1.f, 0, 0, 0);

  // 7) out = relu(r @ W2 + b2)   (reads v-region of d_out are done)
  gemm128<false, true><<<dim3(DHID / 128, M / 128, 1), 256, 0, stream>>>(
      q, W2, b2, nullptr, out, M, DHID, DHID, 1.f, 0, 0, 0);
}

// Round 5
// 780.848 us; speedup vs baseline: 4.9362x; 4.9362x over previous
//
#include <hip/hip_runtime.h>
#include <cstdint>
#include <cstddef>

// Problem dims (fixed by reference)
#define BB   8
#define SS   2048
#define DIN  768
#define DHID 1024

typedef unsigned short u16;
typedef __bf16 bf16x8 __attribute__((ext_vector_type(8)));
typedef float  f32x4  __attribute__((ext_vector_type(4)));

__device__ __forceinline__ u16 f2bf(float f) {
  unsigned u = __float_as_uint(f);
  return (u16)((u + 0x7fffu + ((u >> 16) & 1u)) >> 16);   // RNE
}
__device__ __forceinline__ float bf2f(u16 h) {
  return __uint_as_float((unsigned)h << 16);
}

// async global->LDS, 16B per lane; LDS dest is wave-uniform base + lane*16
#define GLOAD16(g, l)                                                         \
  __builtin_amdgcn_global_load_lds(                                           \
      (const __attribute__((address_space(1))) unsigned int*)(g),             \
      (__attribute__((address_space(3))) unsigned int*)(l), 16, 0, 0)

// ---------------------------------------------------------------------------
// NT bf16 MFMA GEMM (m97 structure): C[M,N] = alpha*A[M,K]@B^T (B given [N,K])
//   + bias + res, optional relu.  Tile 128x128, BK=32, 4 waves, 64x64/wave.
// OUT_MODE: 0 = bf16 [M][N]; 1 = bf16 V-transposed (vT[b][n][s], M=b*2048+s);
//           2 = f32 [M][N]
// ---------------------------------------------------------------------------
template <int OUT_MODE, bool RELU, bool HASRES>
__global__ __launch_bounds__(256)
void gemm_nt(const u16* __restrict__ A, const u16* __restrict__ B,
             const float* __restrict__ bias, const u16* __restrict__ res,
             void* __restrict__ Cv, int M, int N, int K, float alpha,
             long sA, long sB, long sC) {
  __shared__ u16 As[128 * 32];
  __shared__ u16 Bs[128 * 32];

  const int z = blockIdx.z;
  A += (long)z * sA;
  B += (long)z * sB;

  const int tid  = threadIdx.x;
  const int lane = tid & 63;
  const int w    = tid >> 6;          // wave 0..3
  const int bm0  = blockIdx.y * 128;
  const int bn0  = blockIdx.x * 128;
  const int wr   = w >> 1, wc = w & 1;

  // staging: wave w fills rows [w*32, w*32+32) of each 128x32 tile,
  // two global_load_lds per tile (16 rows each): lane l -> row l>>2, col 8*(l&3)
  const int srow = lane >> 2;
  const int scol = (lane & 3) * 8;
  const u16* Ag = A + (long)(bm0 + w * 32 + srow) * K + scol;
  const u16* Bg = B + (long)(bn0 + w * 32 + srow) * K + scol;
  u16* Al0 = As + (w * 32) * 32;
  u16* Al1 = As + (w * 32 + 16) * 32;
  u16* Bl0 = Bs + (w * 32) * 32;
  u16* Bl1 = Bs + (w * 32 + 16) * 32;

  const int fr = lane & 15;           // fragment row/col within 16
  const int fk = (lane >> 4) * 8;     // k-chunk

  f32x4 acc[4][4] = {};

  for (int k0 = 0; k0 < K; k0 += 32) {
    GLOAD16(Ag + k0,                Al0);
    GLOAD16(Ag + k0 + 16 * (long)K, Al1);
    GLOAD16(Bg + k0,                Bl0);
    GLOAD16(Bg + k0 + 16 * (long)K, Bl1);
    __syncthreads();   // compiler drains vmcnt here -> LDS tiles valid

    bf16x8 af[4], bfr[4];
#pragma unroll
    for (int m = 0; m < 4; ++m)
      af[m] = *(const bf16x8*)(As + (wr * 64 + m * 16 + fr) * 32 + fk);
#pragma unroll
    for (int n = 0; n < 4; ++n)
      bfr[n] = *(const bf16x8*)(Bs + (wc * 64 + n * 16 + fr) * 32 + fk);
#pragma unroll
    for (int m = 0; m < 4; ++m)
#pragma unroll
      for (int n = 0; n < 4; ++n)
        acc[m][n] = __builtin_amdgcn_mfma_f32_16x16x32_bf16(af[m], bfr[n],
                                                            acc[m][n], 0, 0, 0);
    __syncthreads();   // protect LDS before next stage
  }

  // epilogue: C/D layout col = lane&15, row = (lane>>4)*4 + reg  [m89/m91]
#pragma unroll
  for (int m = 0; m < 4; ++m) {
    const int row0 = bm0 + wr * 64 + m * 16 + (lane >> 4) * 4;
#pragma unroll
    for (int n = 0; n < 4; ++n) {
      const int col = bn0 + wc * 64 + n * 16 + fr;
      f32x4 v = acc[m][n];
      const float bv = bias ? bias[col] : 0.f;
#pragma unroll
      for (int r = 0; r < 4; ++r) {
        float val = v[r] * alpha + bv;
        if (HASRES) val += bf2f(res[(long)(row0 + r) * N + col]);
        if (RELU)   val = fmaxf(val, 0.f);
        v[r] = val;
      }
      if (OUT_MODE == 0) {
        u16* C = (u16*)Cv + (long)z * sC;
#pragma unroll
        for (int r = 0; r < 4; ++r)
          C[(long)(row0 + r) * N + col] = f2bf(v[r]);
      } else if (OUT_MODE == 1) {
        const int b  = row0 >> 11;       // row = b*2048 + s
        const int s0 = row0 & 2047;      // multiple of 4 -> 8B aligned store
        u16* C = (u16*)Cv + (long)b * (SS * DHID) + (long)col * SS + s0;
        ushort4 p;
        p.x = f2bf(v[0]); p.y = f2bf(v[1]); p.z = f2bf(v[2]); p.w = f2bf(v[3]);
        *(ushort4*)C = p;
      } else {
        float* C = (float*)Cv + (long)z * sC;
#pragma unroll
        for (int r = 0; r < 4; ++r)
          C[(long)(row0 + r) * N + col] = v[r];
      }
    }
  }
}

// ---------------------------------------------------------------------------
// Row softmax over 2048-wide bf16 rows (fp32 internally), one block per row.
// ---------------------------------------------------------------------------
__device__ __forceinline__ float waveReduce(float v, bool isMax) {
#pragma unroll
  for (int off = 32; off > 0; off >>= 1) {
    float o = __shfl_xor(v, off);
    v = isMax ? fmaxf(v, o) : (v + o);
  }
  return v;
}

__global__ __launch_bounds__(256)
void softmax2048b(u16* __restrict__ sc) {
  __shared__ float red[4];
  u16* row = sc + (size_t)blockIdx.x * 2048;
  const int tid = threadIdx.x;
  const int wv = tid >> 6, lane = tid & 63;

  uint4 raw = ((const uint4*)row)[tid];   // 8 bf16
  u16* us = (u16*)&raw;
  float f[8];
#pragma unroll
  for (int i = 0; i < 8; ++i) f[i] = bf2f(us[i]);

  float mx = f[0];
#pragma unroll
  for (int i = 1; i < 8; ++i) mx = fmaxf(mx, f[i]);
  mx = waveReduce(mx, true);
  if (lane == 0) red[wv] = mx;
  __syncthreads();
  mx = fmaxf(fmaxf(red[0], red[1]), fmaxf(red[2], red[3]));
  __syncthreads();

  float s = 0.f;
#pragma unroll
  for (int i = 0; i < 8; ++i) { f[i] = __expf(f[i] - mx); s += f[i]; }
  s = waveReduce(s, false);
  if (lane == 0) red[wv] = s;
  __syncthreads();
  s = red[0] + red[1] + red[2] + red[3];
  const float inv = 1.f / s;

#pragma unroll
  for (int i = 0; i < 8; ++i) us[i] = f2bf(f[i] * inv);
  ((uint4*)row)[tid] = raw;
}

// ---------------------------------------------------------------------------
// fp32 -> bf16 bulk convert (8 elems/thread)
// ---------------------------------------------------------------------------
__global__ __launch_bounds__(256)
void cvt8(const float* __restrict__ in, u16* __restrict__ out, long n) {
  long i = ((long)blockIdx.x * 256 + threadIdx.x) * 8;
  if (i >= n) return;
  float4 a = *(const float4*)(in + i);
  float4 b = *(const float4*)(in + i + 4);
  uint4 o;
  u16* us = (u16*)&o;
  us[0] = f2bf(a.x); us[1] = f2bf(a.y); us[2] = f2bf(a.z); us[3] = f2bf(a.w);
  us[4] = f2bf(b.x); us[5] = f2bf(b.y); us[6] = f2bf(b.z); us[7] = f2bf(b.w);
  *(uint4*)(out + i) = o;
}

// ---------------------------------------------------------------------------
// W [K][N] fp32 -> WT [N][K] bf16  (32x32 LDS tiles)
// ---------------------------------------------------------------------------
__global__ __launch_bounds__(256)
void wtrans(const float* __restrict__ W, u16* __restrict__ WT, int K, int N) {
  __shared__ float t[32][33];
  const int tx = threadIdx.x & 31, ty = threadIdx.x >> 5;   // 32 x 8
  const int n0 = blockIdx.x * 32, k0 = blockIdx.y * 32;
#pragma unroll
  for (int r = 0; r < 32; r += 8)
    t[ty + r][tx] = W[(long)(k0 + ty + r) * N + n0 + tx];
  __syncthreads();
#pragma unroll
  for (int r = 0; r < 32; r += 8)
    WT[(long)(n0 + ty + r) * K + k0 + tx] = f2bf(t[tx][ty + r]);
}

// ---------------------------------------------------------------------------
extern "C" void kernel_launch(void* const* d_in, const int* in_sizes, int n_in,
                              void* d_out, int out_size, void* d_ws, size_t ws_size,
                              hipStream_t stream) {
  const float* x  = (const float*)d_in[0];
  const float* W1 = (const float*)d_in[1];
  const float* b1 = (const float*)d_in[2];
  const float* Wq = (const float*)d_in[3];
  const float* bq = (const float*)d_in[4];
  const float* Wk = (const float*)d_in[5];
  const float* bk = (const float*)d_in[6];
  const float* Wv = (const float*)d_in[7];
  const float* bv = (const float*)d_in[8];
  const float* W2 = (const float*)d_in[9];
  const float* b2 = (const float*)d_in[10];
  const float* Wsm = (const float*)d_in[11];
  const float* bs = (const float*)d_in[12];
  float* out = (float*)d_out;

  const long M   = (long)BB * SS;        // 16384
  const long MD  = M * DHID;             // 16.77M
  const long SD  = (long)SS * DHID;      // per-batch stride
  const long SSq = (long)SS * SS;        // per-batch score elems
  const long NX  = M * DIN;              // x elems

  // workspace layout (u16 elements):
  u16* wsb = (u16*)d_ws;
  u16* xb  = wsb;                        // [M][768]
  u16* W1T = xb  + NX;                   // [1024][768]
  u16* WqT = W1T + (long)DHID * DIN;     // [1024][1024]
  u16* WkT = WqT + (long)DHID * DHID;
  u16* WvT = WkT + (long)DHID * DHID;
  u16* W2T = WvT + (long)DHID * DHID;
  u16* WsT = W2T + (long)DHID * DHID;    // [1024][768]
  u16* h   = WsT + (long)DHID * DIN;     // [M][1024] bf16
  u16* q   = h + MD;
  u16* k   = q + MD;
  u16* scores = k + MD;                  // chunked
  u16* vT  = (u16*)d_out;                // [B][1024][2048] bf16, dead before final GEMM

  long avail = (long)(ws_size / 2) - (scores - wsb);
  int nb = (int)(avail / SSq);
  if (nb > BB) nb = BB;
  if (nb < 1) nb = 1;

  // --- convert inputs to bf16 (and transpose weights) ---
  cvt8<<<(unsigned)((NX / 8 + 255) / 256), 256, 0, stream>>>(x, xb, NX);
  wtrans<<<dim3(DHID / 32, DIN / 32), 256, 0, stream>>>(W1, W1T, DIN, DHID);
  wtrans<<<dim3(DHID / 32, DHID / 32), 256, 0, stream>>>(Wq, WqT, DHID, DHID);
  wtrans<<<dim3(DHID / 32, DHID / 32), 256, 0, stream>>>(Wk, WkT, DHID, DHID);
  wtrans<<<dim3(DHID / 32, DHID / 32), 256, 0, stream>>>(Wv, WvT, DHID, DHID);
  wtrans<<<dim3(DHID / 32, DHID / 32), 256, 0, stream>>>(W2, W2T, DHID, DHID);
  wtrans<<<dim3(DHID / 32, DIN / 32), 256, 0, stream>>>(Wsm, WsT, DIN, DHID);

  const dim3 gMain(DHID / 128, M / 128, 1);   // (8,128)

  // 1) h = relu(x @ W1 + b1)
  gemm_nt<0, true, false><<<gMain, 256, 0, stream>>>(
      xb, W1T, b1, nullptr, h, (int)M, DHID, DIN, 1.f, 0, 0, 0);
  // 2) q,k (bf16), v (transposed per batch)
  gemm_nt<0, false, false><<<gMain, 256, 0, stream>>>(
      h, WqT, bq, nullptr, q, (int)M, DHID, DHID, 1.f, 0, 0, 0);
  gemm_nt<0, false, false><<<gMain, 256, 0, stream>>>(
      h, WkT, bk, nullptr, k, (int)M, DHID, DHID, 1.f, 0, 0, 0);
  gemm_nt<1, false, false><<<gMain, 256, 0, stream>>>(
      h, WvT, bv, nullptr, vT, (int)M, DHID, DHID, 1.f, 0, 0, 0);

  // 3-5) attention, chunked over batches to fit scores in ws
  const float scale = 0.03125f;  // 1/sqrt(1024)
  for (int b0 = 0; b0 < BB; b0 += nb) {
    const int cb = (b0 + nb <= BB) ? nb : (BB - b0);
    gemm_nt<0, false, false><<<dim3(SS / 128, SS / 128, cb), 256, 0, stream>>>(
        q + (long)b0 * SD, k + (long)b0 * SD, nullptr, nullptr, scores,
        SS, SS, DHID, scale, SD, SD, SSq);
    softmax2048b<<<cb * SS, 256, 0, stream>>>(scores);
    gemm_nt<0, false, false><<<dim3(DHID / 128, SS / 128, cb), 256, 0, stream>>>(
        scores, vT + (long)b0 * SD, nullptr, nullptr, h + (long)b0 * SD,
        SS, DHID, SS, 1.f, SSq, SD, SD);
  }

  // 6) r = x @ Ws + bs + attn_out   (attn_out bf16 in h; r -> q region)
  gemm_nt<0, false, true><<<gMain, 256, 0, stream>>>(
      xb, WsT, bs, h, q, (int)M, DHID, DIN, 1.f, 0, 0, 0);

  // 7) out = relu(r @ W2 + b2) -> fp32 d_out (vT region dead by now)
  gemm_nt<2, true, false><<<gMain, 256, 0, stream>>>(
      q, W2T, b2, nullptr, out, (int)M, DHID, DHID, 1.f, 0, 0, 0);
}

// Round 6
// 602.243 us; speedup vs baseline: 6.4001x; 1.2966x over previous
//
#include <hip/hip_runtime.h>
#include <cstdint>
#include <cstddef>

// Problem dims (fixed by reference)
#define BB   8
#define SS   2048
#define DIN  768
#define DHID 1024

typedef unsigned short u16;
typedef __bf16 bf16x8 __attribute__((ext_vector_type(8)));
typedef float  f32x4  __attribute__((ext_vector_type(4)));

__device__ __forceinline__ u16 f2bf(float f) {
  unsigned u = __float_as_uint(f);
  return (u16)((u + 0x7fffu + ((u >> 16) & 1u)) >> 16);   // RNE
}
__device__ __forceinline__ float bf2f(u16 h) {
  return __uint_as_float((unsigned)h << 16);
}

// async global->LDS, 16B per lane; LDS dest = wave-uniform base + lane*16
#define GLOAD16(g, l)                                                         \
  __builtin_amdgcn_global_load_lds(                                           \
      (const __attribute__((address_space(1))) unsigned int*)(g),             \
      (__attribute__((address_space(3))) unsigned int*)(l), 16, 0, 0)

// ---------------------------------------------------------------------------
// NT bf16 MFMA GEMM, 256x256 tile, BK=32, 8 waves (2M x 4N), ring-4 LDS
// double-buffer with counted vmcnt (T3+T4), XOR-swizzled LDS (T2), setprio
// (T5), XCD-aware block swizzle (T1).
// C[M,N] = alpha*A[M,K]@B^T (B given [N,K]) + bias + res, optional relu.
// LDS tile layout: element (r,c) of a [256][32] tile stored at column
//   c ^ ((r&6)<<2)  -> 2-way max bank aliasing on frag reads (free, m136).
// Staging writes linearly (global_load_lds); swizzle folded into the GLOBAL
// source address (both-sides-or-neither, rule #21).
// Ring-4: tile t lives in buf t&3; stage(t+3) issued in iter t targets a
// buffer last read in iter t-1 (reads pinned by lgkmcnt(0) before that
// iteration's barrier) -> no region hazard. vmcnt(8) at end of iter t
// guarantees tile t+1 (issued iter t-2, 3rd-oldest half-set) has landed.
// OUT_MODE: 0 = bf16 [M][N]; 1 = bf16 V-transposed (vT[b][n][s]); 2 = f32.
// ---------------------------------------------------------------------------
template <int OUT_MODE, bool RELU, bool HASRES>
__global__ __launch_bounds__(512, 2)
void gemm256(const u16* __restrict__ A, const u16* __restrict__ B,
             const float* __restrict__ bias, const u16* __restrict__ res,
             void* __restrict__ Cv, int M, int N, int K, float alpha,
             long strA, long strB, long strC) {
  __shared__ u16 sA[4][8192];   // 4 x 16KB
  __shared__ u16 sB[4][8192];   // 4 x 16KB   -> 128 KiB total

  // T1: bijective XCD swizzle of flattened block id (all grids %8 == 0)
  const int nbx = gridDim.x, nby = gridDim.y;
  const long nwg  = (long)nbx * nby * gridDim.z;
  const long orig = blockIdx.x + (long)nbx * (blockIdx.y + (long)nby * blockIdx.z);
  const long per  = nwg >> 3;
  const long swz  = (orig & 7) * per + (orig >> 3);
  const int  bz   = (int)(swz / ((long)nbx * nby));
  const int  rem  = (int)(swz % ((long)nbx * nby));
  const int  by   = rem / nbx, bx = rem % nbx;

  A += (long)bz * strA;
  B += (long)bz * strB;

  const int tid  = threadIdx.x;
  const int lane = tid & 63;
  const int w    = tid >> 6;          // wave 0..7
  const int wr   = w >> 2;            // M half (0..1), 128 rows
  const int wc   = w & 3;             // N quarter (0..3), 64 cols
  const int bm0  = by * 256;
  const int bn0  = bx * 256;

  // staging: wave w stages rows [w*32, w*32+32) of each 256x32 tile.
  // lane l -> row chunk + l/4, phys col 8*(l&3); global col pre-swizzled.
  const int sr    = lane >> 2;
  const int clog  = ((lane & 3) * 8) ^ (((lane >> 2) & 6) << 2);
  const u16* AgBase = A + (long)(bm0 + w * 32 + sr) * K + clog;
  const u16* BgBase = B + (long)(bn0 + w * 32 + sr) * K + clog;

  // frag reads: row = ... + fr, col = fk ^ ((fr&6)<<2)  (swizzled)
  const int fr = lane & 15;
  const int fk = (lane >> 4) * 8;
  const int ck = fk ^ ((fr & 6) << 2);

  f32x4 acc[8][4] = {};
  const int T = K >> 5;               // K-tiles of 32 (K%32==0, T>=24)

  auto stage = [&](int t) {
    const int bf_ = t & 3;
    const long k0 = (long)t * 32;
    u16* la = &sA[bf_][(w * 32) * 32];
    u16* lb = &sB[bf_][(w * 32) * 32];
    GLOAD16(AgBase + k0,                 la);
    GLOAD16(AgBase + k0 + 16 * (long)K,  la + 16 * 32);
    GLOAD16(BgBase + k0,                 lb);
    GLOAD16(BgBase + k0 + 16 * (long)K,  lb + 16 * 32);
  };

  // prologue: tiles 0,1,2 in flight (12 loads); wait oldest 4 (tile 0)
  stage(0); stage(1); stage(2);
  asm volatile("s_waitcnt vmcnt(8)" ::: "memory");
  __builtin_amdgcn_s_barrier();
  __builtin_amdgcn_sched_barrier(0);

  for (int t = 0; t < T; ++t) {
    if (t + 3 < T) stage(t + 3);      // -> buf (t+3)&3, free since iter t-1

    const int b = t & 3;
    bf16x8 af[8], bfv[4];
#pragma unroll
    for (int m = 0; m < 8; ++m)
      af[m] = *(const bf16x8*)(&sA[b][(wr * 128 + m * 16 + fr) * 32 + ck]);
#pragma unroll
    for (int n = 0; n < 4; ++n)
      bfv[n] = *(const bf16x8*)(&sB[b][(wc * 64 + n * 16 + fr) * 32 + ck]);

    // reads done before barrier (cross-wave: next iter's stages may target
    // this buffer region set only after every wave passed this barrier)
    asm volatile("s_waitcnt lgkmcnt(0)" ::: "memory");
    // T4: counted vmcnt — tile t+1 (3rd-oldest 4-load set) landed; never
    // drain to 0 in steady state
    if (t + 3 < T)      asm volatile("s_waitcnt vmcnt(8)" ::: "memory");
    else if (t + 2 < T) asm volatile("s_waitcnt vmcnt(4)" ::: "memory");
    else                asm volatile("s_waitcnt vmcnt(0)" ::: "memory");
    __builtin_amdgcn_s_barrier();
    __builtin_amdgcn_sched_barrier(0);

    __builtin_amdgcn_s_setprio(1);    // T5
#pragma unroll
    for (int m = 0; m < 8; ++m)
#pragma unroll
      for (int n = 0; n < 4; ++n)
        acc[m][n] = __builtin_amdgcn_mfma_f32_16x16x32_bf16(af[m], bfv[n],
                                                            acc[m][n], 0, 0, 0);
    __builtin_amdgcn_s_setprio(0);
  }

  // epilogue: D layout col = lane&15, row = (lane>>4)*4 + reg  [m89/m91]
#pragma unroll
  for (int m = 0; m < 8; ++m) {
    const int row0 = bm0 + wr * 128 + m * 16 + (lane >> 4) * 4;
#pragma unroll
    for (int n = 0; n < 4; ++n) {
      const int col = bn0 + wc * 64 + n * 16 + fr;
      f32x4 v = acc[m][n];
      const float bvv = bias ? bias[col] : 0.f;
#pragma unroll
      for (int r = 0; r < 4; ++r) {
        float val = v[r] * alpha + bvv;
        if (HASRES) val += bf2f(res[(long)(row0 + r) * N + col]);
        if (RELU)   val = fmaxf(val, 0.f);
        v[r] = val;
      }
      if (OUT_MODE == 0) {
        u16* C = (u16*)Cv + (long)bz * strC;
#pragma unroll
        for (int r = 0; r < 4; ++r)
          C[(long)(row0 + r) * N + col] = f2bf(v[r]);
      } else if (OUT_MODE == 1) {
        const int bb = row0 >> 11;       // row = b*2048 + s
        const int s0 = row0 & 2047;      // multiple of 4 -> 8B aligned
        u16* C = (u16*)Cv + (long)bb * (SS * DHID) + (long)col * SS + s0;
        ushort4 p;
        p.x = f2bf(v[0]); p.y = f2bf(v[1]); p.z = f2bf(v[2]); p.w = f2bf(v[3]);
        *(ushort4*)C = p;
      } else {
        float* C = (float*)Cv + (long)bz * strC;
#pragma unroll
        for (int r = 0; r < 4; ++r)
          C[(long)(row0 + r) * N + col] = v[r];
      }
    }
  }
}

// ---------------------------------------------------------------------------
// Row softmax over 2048-wide bf16 rows (fp32 internally), one block per row.
// ---------------------------------------------------------------------------
__device__ __forceinline__ float waveReduce(float v, bool isMax) {
#pragma unroll
  for (int off = 32; off > 0; off >>= 1) {
    float o = __shfl_xor(v, off);
    v = isMax ? fmaxf(v, o) : (v + o);
  }
  return v;
}

__global__ __launch_bounds__(256)
void softmax2048b(u16* __restrict__ sc) {
  __shared__ float red[4];
  u16* row = sc + (size_t)blockIdx.x * 2048;
  const int tid = threadIdx.x;
  const int wv = tid >> 6, lane = tid & 63;

  uint4 raw = ((const uint4*)row)[tid];   // 8 bf16
  u16* us = (u16*)&raw;
  float f[8];
#pragma unroll
  for (int i = 0; i < 8; ++i) f[i] = bf2f(us[i]);

  float mx = f[0];
#pragma unroll
  for (int i = 1; i < 8; ++i) mx = fmaxf(mx, f[i]);
  mx = waveReduce(mx, true);
  if (lane == 0) red[wv] = mx;
  __syncthreads();
  mx = fmaxf(fmaxf(red[0], red[1]), fmaxf(red[2], red[3]));
  __syncthreads();

  float s = 0.f;
#pragma unroll
  for (int i = 0; i < 8; ++i) { f[i] = __expf(f[i] - mx); s += f[i]; }
  s = waveReduce(s, false);
  if (lane == 0) red[wv] = s;
  __syncthreads();
  s = red[0] + red[1] + red[2] + red[3];
  const float inv = 1.f / s;

#pragma unroll
  for (int i = 0; i < 8; ++i) us[i] = f2bf(f[i] * inv);
  ((uint4*)row)[tid] = raw;
}

// ---------------------------------------------------------------------------
// fp32 -> bf16 bulk convert (8 elems/thread)
// ---------------------------------------------------------------------------
__global__ __launch_bounds__(256)
void cvt8(const float* __restrict__ in, u16* __restrict__ out, long n) {
  long i = ((long)blockIdx.x * 256 + threadIdx.x) * 8;
  if (i >= n) return;
  float4 a = *(const float4*)(in + i);
  float4 b = *(const float4*)(in + i + 4);
  uint4 o;
  u16* us = (u16*)&o;
  us[0] = f2bf(a.x); us[1] = f2bf(a.y); us[2] = f2bf(a.z); us[3] = f2bf(a.w);
  us[4] = f2bf(b.x); us[5] = f2bf(b.y); us[6] = f2bf(b.z); us[7] = f2bf(b.w);
  *(uint4*)(out + i) = o;
}

// ---------------------------------------------------------------------------
// W [K][N] fp32 -> WT [N][K] bf16  (32x32 LDS tiles)
// ---------------------------------------------------------------------------
__global__ __launch_bounds__(256)
void wtrans(const float* __restrict__ W, u16* __restrict__ WT, int K, int N) {
  __shared__ float t[32][33];
  const int tx = threadIdx.x & 31, ty = threadIdx.x >> 5;   // 32 x 8
  const int n0 = blockIdx.x * 32, k0 = blockIdx.y * 32;
#pragma unroll
  for (int r = 0; r < 32; r += 8)
    t[ty + r][tx] = W[(long)(k0 + ty + r) * N + n0 + tx];
  __syncthreads();
#pragma unroll
  for (int r = 0; r < 32; r += 8)
    WT[(long)(n0 + ty + r) * K + k0 + tx] = f2bf(t[tx][ty + r]);
}

// ---------------------------------------------------------------------------
extern "C" void kernel_launch(void* const* d_in, const int* in_sizes, int n_in,
                              void* d_out, int out_size, void* d_ws, size_t ws_size,
                              hipStream_t stream) {
  const float* x  = (const float*)d_in[0];
  const float* W1 = (const float*)d_in[1];
  const float* b1 = (const float*)d_in[2];
  const float* Wq = (const float*)d_in[3];
  const float* bq = (const float*)d_in[4];
  const float* Wk = (const float*)d_in[5];
  const float* bk = (const float*)d_in[6];
  const float* Wv = (const float*)d_in[7];
  const float* bv = (const float*)d_in[8];
  const float* W2 = (const float*)d_in[9];
  const float* b2 = (const float*)d_in[10];
  const float* Wsm = (const float*)d_in[11];
  const float* bs = (const float*)d_in[12];
  float* out = (float*)d_out;

  const long M   = (long)BB * SS;        // 16384
  const long MD  = M * DHID;             // 16.77M
  const long SD  = (long)SS * DHID;      // per-batch stride
  const long SSq = (long)SS * SS;        // per-batch score elems
  const long NX  = M * DIN;              // x elems

  // workspace layout (u16 elements):
  u16* wsb = (u16*)d_ws;
  u16* xb  = wsb;                        // [M][768]
  u16* W1T = xb  + NX;                   // [1024][768]
  u16* WqT = W1T + (long)DHID * DIN;     // [1024][1024]
  u16* WkT = WqT + (long)DHID * DHID;
  u16* WvT = WkT + (long)DHID * DHID;
  u16* W2T = WvT + (long)DHID * DHID;
  u16* WsT = W2T + (long)DHID * DHID;    // [1024][768]
  u16* h   = WsT + (long)DHID * DIN;     // [M][1024] bf16
  u16* q   = h + MD;
  u16* k   = q + MD;
  u16* scores = k + MD;                  // chunked
  u16* vT  = (u16*)d_out;                // [B][1024][2048] bf16, dead before final GEMM

  long avail = (long)(ws_size / 2) - (scores - wsb);
  int nb = (int)(avail / SSq);
  if (nb > BB) nb = BB;
  if (nb < 1) nb = 1;

  // --- convert inputs to bf16 (and transpose weights) ---
  cvt8<<<(unsigned)((NX / 8 + 255) / 256), 256, 0, stream>>>(x, xb, NX);
  wtrans<<<dim3(DHID / 32, DIN / 32), 256, 0, stream>>>(W1, W1T, DIN, DHID);
  wtrans<<<dim3(DHID / 32, DHID / 32), 256, 0, stream>>>(Wq, WqT, DHID, DHID);
  wtrans<<<dim3(DHID / 32, DHID / 32), 256, 0, stream>>>(Wk, WkT, DHID, DHID);
  wtrans<<<dim3(DHID / 32, DHID / 32), 256, 0, stream>>>(Wv, WvT, DHID, DHID);
  wtrans<<<dim3(DHID / 32, DHID / 32), 256, 0, stream>>>(W2, W2T, DHID, DHID);
  wtrans<<<dim3(DHID / 32, DIN / 32), 256, 0, stream>>>(Wsm, WsT, DIN, DHID);

  const dim3 gMain(DHID / 256, M / 256, 1);   // (4,64) = 256 blocks

  // 1) h = relu(x @ W1 + b1)
  gemm256<0, true, false><<<gMain, 512, 0, stream>>>(
      xb, W1T, b1, nullptr, h, (int)M, DHID, DIN, 1.f, 0, 0, 0);
  // 2) q,k (bf16), v (transposed per batch)
  gemm256<0, false, false><<<gMain, 512, 0, stream>>>(
      h, WqT, bq, nullptr, q, (int)M, DHID, DHID, 1.f, 0, 0, 0);
  gemm256<0, false, false><<<gMain, 512, 0, stream>>>(
      h, WkT, bk, nullptr, k, (int)M, DHID, DHID, 1.f, 0, 0, 0);
  gemm256<1, false, false><<<gMain, 512, 0, stream>>>(
      h, WvT, bv, nullptr, vT, (int)M, DHID, DHID, 1.f, 0, 0, 0);

  // 3-5) attention, chunked over batches to fit scores in ws
  const float scale = 0.03125f;  // 1/sqrt(1024)
  for (int b0 = 0; b0 < BB; b0 += nb) {
    const int cb = (b0 + nb <= BB) ? nb : (BB - b0);
    gemm256<0, false, false><<<dim3(SS / 256, SS / 256, cb), 512, 0, stream>>>(
        q + (long)b0 * SD, k + (long)b0 * SD, nullptr, nullptr, scores,
        SS, SS, DHID, scale, SD, SD, SSq);
    softmax2048b<<<cb * SS, 256, 0, stream>>>(scores);
    gemm256<0, false, false><<<dim3(DHID / 256, SS / 256, cb), 512, 0, stream>>>(
        scores, vT + (long)b0 * SD, nullptr, nullptr, h + (long)b0 * SD,
        SS, DHID, SS, 1.f, SSq, SD, SD);
  }

  // 6) r = x @ Ws + bs + attn_out   (attn_out bf16 in h; r -> q region)
  gemm256<0, false, true><<<gMain, 512, 0, stream>>>(
      xb, WsT, bs, h, q, (int)M, DHID, DIN, 1.f, 0, 0, 0);

  // 7) out = relu(r @ W2 + b2) -> fp32 d_out (vT region dead by now)
  gemm256<2, true, false><<<gMain, 512, 0, stream>>>(
      q, W2T, b2, nullptr, out, (int)M, DHID, DHID, 1.f, 0, 0, 0);
}

// Round 8
// 549.554 us; speedup vs baseline: 7.0137x; 1.0959x over previous
//
#include <hip/hip_runtime.h>
#include <cstdint>
#include <cstddef>

// Problem dims (fixed by reference)
#define BB   8
#define SS   2048
#define DIN  768
#define DHID 1024

typedef unsigned short u16;
typedef __bf16 bf16x8 __attribute__((ext_vector_type(8)));
typedef float  f32x4  __attribute__((ext_vector_type(4)));

__device__ __forceinline__ u16 f2bf(float f) {
  unsigned u = __float_as_uint(f);
  return (u16)((u + 0x7fffu + ((u >> 16) & 1u)) >> 16);   // RNE
}
__device__ __forceinline__ float bf2f(u16 h) {
  return __uint_as_float((unsigned)h << 16);
}

// async global->LDS, 16B per lane; LDS dest = wave-uniform base + lane*16
#define GLOAD16(g, l)                                                         \
  __builtin_amdgcn_global_load_lds(                                           \
      (const __attribute__((address_space(1))) unsigned int*)(g),             \
      (__attribute__((address_space(3))) unsigned int*)(l), 16, 0, 0)

#define SB0()  __builtin_amdgcn_sched_barrier(0)
#define BAR()  __builtin_amdgcn_s_barrier()

// ---------------------------------------------------------------------------
// NT bf16 MFMA GEMM, 256x256 tile, BK=64, 8 waves (2M x 4N), m201-style
// 4-phase/K-tile schedule: per phase {4-8 ds_read || 1 half-tile stage ->
// barrier -> 16 MFMA (setprio) -> [vmcnt(4) at K-tile boundary] -> barrier}.
// dbuf x2 LDS (128 KiB), K-half staging granularity (2 gload_lds / thread).
// vmcnt ledger (loads/thread): prologue issues 8 (k0,k1 of tile0), waits
// vmcnt(4) [k0 landed]. Steady: p0 stages Ak0(t+1), p1 stages Bk0(t+1) then
// vmcnt(4) drains k1(t) before p2 reads it; p2 stages Ak1(t+1), p3 stages
// Bk1(t+1) then vmcnt(4) drains k0(t+1) for next group. Never 0 mid-loop.
// Cross-wave safety: every vmcnt drain precedes a barrier that precedes the
// dependent ds_reads; LDS reads drain in-phase (FIFO lgkmcnt + MFMA waits)
// >=3 barriers before any stage rewrites their region.
// LDS swizzle (bank-conflict-free, measured 0 in r6): phys col =
//   c ^ ((r&6)<<2); staging pre-swizzles the GLOBAL source col (rule #21).
// OUT_MODE: 0 = bf16 [M][N]; 1 = bf16 V-transposed (vT[b][n][s]); 2 = f32.
// ---------------------------------------------------------------------------
template <int OUT_MODE, bool RELU, bool HASRES>
__global__ __launch_bounds__(512)
void gemm256(const u16* __restrict__ A, const u16* __restrict__ B,
             const float* __restrict__ bias, const u16* __restrict__ res,
             void* __restrict__ Cv, int M, int N, int K, float alpha,
             long strA, long strB, long strC) {
  __shared__ u16 sA[2][2][8192];   // [slot][khalf][256 rows * 32 cols]
  __shared__ u16 sB[2][2][8192];   // 128 KiB total

  // T1: bijective XCD swizzle of flattened block id (all grids %8 == 0)
  const int nbx = gridDim.x, nby = gridDim.y;
  const long nwg  = (long)nbx * nby * gridDim.z;
  const long orig = blockIdx.x + (long)nbx * (blockIdx.y + (long)nby * blockIdx.z);
  const long per  = nwg >> 3;
  const long swz  = (orig & 7) * per + (orig >> 3);
  const int  bz   = (int)(swz / ((long)nbx * nby));
  const int  rem  = (int)(swz % ((long)nbx * nby));
  const int  by   = rem / nbx, bx = rem % nbx;

  A += (long)bz * strA;
  B += (long)bz * strB;

  const int tid  = threadIdx.x;
  const int lane = tid & 63;
  const int w    = tid >> 6;          // wave 0..7
  const int wr   = w >> 2;            // M half (0..1), 128 rows
  const int wc   = w & 3;             // N quarter (0..3), 64 cols
  const int bm0  = by * 256;
  const int bn0  = bx * 256;

  // staging: wave w stages rows [w*32, w*32+32) of a 256x32 k-half.
  // lane l -> row w*32 + (l>>2), chunk (l&3)*8; source col pre-swizzled.
  const int sr   = lane >> 2;
  const int clog = ((lane & 3) * 8) ^ (((lane >> 2) & 6) << 2);
  const u16* Ag = A + (long)(bm0 + w * 32 + sr) * K + clog;
  const u16* Bg = B + (long)(bn0 + w * 32 + sr) * K + clog;

  // frag reads: row = base + fr, col = fk ^ ((fr&6)<<2)
  const int fr = lane & 15;
  const int fk = (lane >> 4) * 8;
  const int ck = fk ^ ((fr & 6) << 2);
  const int aoff = (wr * 128 + fr) * 32 + ck;   // u16 units within [8192]
  const int boff = (wc * 64  + fr) * 32 + ck;

  auto stageA = [&](int slot, int ks, int t) {
    u16* d = &sA[slot][ks][(w * 32) * 32];
    const u16* g = Ag + (long)t * 64 + ks * 32;
    GLOAD16(g, d);
    GLOAD16(g + 16 * (long)K, d + 512);
  };
  auto stageB = [&](int slot, int ks, int t) {
    u16* d = &sB[slot][ks][(w * 32) * 32];
    const u16* g = Bg + (long)t * 64 + ks * 32;
    GLOAD16(g, d);
    GLOAD16(g + 16 * (long)K, d + 512);
  };

  f32x4 acc[8][4] = {};
  bf16x8 af[4], bfv[4];
  const int T = K >> 6;               // K-tiles of 64; K in {768,1024,2048}

  // ---- prologue: tile 0 fully issued; k0 guaranteed, k1 left in flight ----
  stageA(0, 0, 0); stageB(0, 0, 0); stageA(0, 1, 0); stageB(0, 1, 0);
  asm volatile("s_waitcnt vmcnt(4)" ::: "memory");
  BAR(); SB0();

  for (int t = 0; t < T; ++t) {
    const int s = t & 1, s1 = s ^ 1;
    const bool pf = (t + 1 < T);

    // ---- phase 0: reads A m0-3@k0 + B n0-3@k0; stage Ak0(t+1) ----
#pragma unroll
    for (int m = 0; m < 4; ++m)
      af[m] = *(const bf16x8*)(&sA[s][0][aoff + m * 512]);
#pragma unroll
    for (int n = 0; n < 4; ++n)
      bfv[n] = *(const bf16x8*)(&sB[s][0][boff + n * 512]);
    if (pf) stageA(s1, 0, t + 1);
    SB0(); BAR(); SB0();
    __builtin_amdgcn_s_setprio(1);
#pragma unroll
    for (int m = 0; m < 4; ++m)
#pragma unroll
      for (int n = 0; n < 4; ++n)
        acc[m][n] = __builtin_amdgcn_mfma_f32_16x16x32_bf16(af[m], bfv[n],
                                                            acc[m][n], 0, 0, 0);
    __builtin_amdgcn_s_setprio(0);
    BAR(); SB0();

    // ---- phase 1: reads A m4-7@k0; stage Bk0(t+1); vmcnt -> k1(t) ready ----
#pragma unroll
    for (int m = 0; m < 4; ++m)
      af[m] = *(const bf16x8*)(&sA[s][0][aoff + (m + 4) * 512]);
    if (pf) stageB(s1, 0, t + 1);
    SB0(); BAR(); SB0();
    __builtin_amdgcn_s_setprio(1);
#pragma unroll
    for (int m = 0; m < 4; ++m)
#pragma unroll
      for (int n = 0; n < 4; ++n)
        acc[m + 4][n] = __builtin_amdgcn_mfma_f32_16x16x32_bf16(af[m], bfv[n],
                                                                acc[m + 4][n], 0, 0, 0);
    __builtin_amdgcn_s_setprio(0);
    if (pf) asm volatile("s_waitcnt vmcnt(4)" ::: "memory");
    else    asm volatile("s_waitcnt vmcnt(0)" ::: "memory");
    BAR(); SB0();

    // ---- phase 2: reads A m0-3@k1 + B n0-3@k1; stage Ak1(t+1) ----
#pragma unroll
    for (int m = 0; m < 4; ++m)
      af[m] = *(const bf16x8*)(&sA[s][1][aoff + m * 512]);
#pragma unroll
    for (int n = 0; n < 4; ++n)
      bfv[n] = *(const bf16x8*)(&sB[s][1][boff + n * 512]);
    if (pf) stageA(s1, 1, t + 1);
    SB0(); BAR(); SB0();
    __builtin_amdgcn_s_setprio(1);
#pragma unroll
    for (int m = 0; m < 4; ++m)
#pragma unroll
      for (int n = 0; n < 4; ++n)
        acc[m][n] = __builtin_amdgcn_mfma_f32_16x16x32_bf16(af[m], bfv[n],
                                                            acc[m][n], 0, 0, 0);
    __builtin_amdgcn_s_setprio(0);
    BAR(); SB0();

    // ---- phase 3: reads A m4-7@k1; stage Bk1(t+1); vmcnt -> k0(t+1) ready --
#pragma unroll
    for (int m = 0; m < 4; ++m)
      af[m] = *(const bf16x8*)(&sA[s][1][aoff + (m + 4) * 512]);
    if (pf) stageB(s1, 1, t + 1);
    SB0(); BAR(); SB0();
    __builtin_amdgcn_s_setprio(1);
#pragma unroll
    for (int m = 0; m < 4; ++m)
#pragma unroll
      for (int n = 0; n < 4; ++n)
        acc[m + 4][n] = __builtin_amdgcn_mfma_f32_16x16x32_bf16(af[m], bfv[n],
                                                                acc[m + 4][n], 0, 0, 0);
    __builtin_amdgcn_s_setprio(0);
    if (pf) asm volatile("s_waitcnt vmcnt(4)" ::: "memory");
    else    asm volatile("s_waitcnt vmcnt(0)" ::: "memory");
    BAR(); SB0();
  }

  // epilogue: D layout col = lane&15, row = (lane>>4)*4 + reg  [m89/m91]
#pragma unroll
  for (int m = 0; m < 8; ++m) {
    const int row0 = bm0 + wr * 128 + m * 16 + (lane >> 4) * 4;
#pragma unroll
    for (int n = 0; n < 4; ++n) {
      const int col = bn0 + wc * 64 + n * 16 + fr;
      f32x4 v = acc[m][n];
      const float bvv = bias ? bias[col] : 0.f;
#pragma unroll
      for (int r = 0; r < 4; ++r) {
        float val = v[r] * alpha + bvv;
        if (HASRES) val += bf2f(res[(long)(row0 + r) * N + col]);
        if (RELU)   val = fmaxf(val, 0.f);
        v[r] = val;
      }
      if (OUT_MODE == 0) {
        u16* C = (u16*)Cv + (long)bz * strC;
#pragma unroll
        for (int r = 0; r < 4; ++r)
          C[(long)(row0 + r) * N + col] = f2bf(v[r]);
      } else if (OUT_MODE == 1) {
        const int bb = row0 >> 11;       // row = b*2048 + s
        const int s0 = row0 & 2047;      // multiple of 4 -> 8B aligned
        u16* C = (u16*)Cv + (long)bb * (SS * DHID) + (long)col * SS + s0;
        ushort4 p;
        p.x = f2bf(v[0]); p.y = f2bf(v[1]); p.z = f2bf(v[2]); p.w = f2bf(v[3]);
        *(ushort4*)C = p;
      } else {
        float* C = (float*)Cv + (long)bz * strC;
#pragma unroll
        for (int r = 0; r < 4; ++r)
          C[(long)(row0 + r) * N + col] = v[r];
      }
    }
  }
}

// ---------------------------------------------------------------------------
// Row softmax over 2048-wide bf16 rows (fp32 internally), one block per row.
// ---------------------------------------------------------------------------
__device__ __forceinline__ float waveReduce(float v, bool isMax) {
#pragma unroll
  for (int off = 32; off > 0; off >>= 1) {
    float o = __shfl_xor(v, off);
    v = isMax ? fmaxf(v, o) : (v + o);
  }
  return v;
}

__global__ __launch_bounds__(256)
void softmax2048b(u16* __restrict__ sc) {
  __shared__ float red[4];
  u16* row = sc + (size_t)blockIdx.x * 2048;
  const int tid = threadIdx.x;
  const int wv = tid >> 6, lane = tid & 63;

  uint4 raw = ((const uint4*)row)[tid];   // 8 bf16
  u16* us = (u16*)&raw;
  float f[8];
#pragma unroll
  for (int i = 0; i < 8; ++i) f[i] = bf2f(us[i]);

  float mx = f[0];
#pragma unroll
  for (int i = 1; i < 8; ++i) mx = fmaxf(mx, f[i]);
  mx = waveReduce(mx, true);
  if (lane == 0) red[wv] = mx;
  __syncthreads();
  mx = fmaxf(fmaxf(red[0], red[1]), fmaxf(red[2], red[3]));
  __syncthreads();

  float s = 0.f;
#pragma unroll
  for (int i = 0; i < 8; ++i) { f[i] = __expf(f[i] - mx); s += f[i]; }
  s = waveReduce(s, false);
  if (lane == 0) red[wv] = s;
  __syncthreads();
  s = red[0] + red[1] + red[2] + red[3];
  const float inv = 1.f / s;

#pragma unroll
  for (int i = 0; i < 8; ++i) us[i] = f2bf(f[i] * inv);
  ((uint4*)row)[tid] = raw;
}

// ---------------------------------------------------------------------------
// fp32 -> bf16 bulk convert (8 elems/thread)
// ---------------------------------------------------------------------------
__global__ __launch_bounds__(256)
void cvt8(const float* __restrict__ in, u16* __restrict__ out, long n) {
  long i = ((long)blockIdx.x * 256 + threadIdx.x) * 8;
  if (i >= n) return;
  float4 a = *(const float4*)(in + i);
  float4 b = *(const float4*)(in + i + 4);
  uint4 o;
  u16* us = (u16*)&o;
  us[0] = f2bf(a.x); us[1] = f2bf(a.y); us[2] = f2bf(a.z); us[3] = f2bf(a.w);
  us[4] = f2bf(b.x); us[5] = f2bf(b.y); us[6] = f2bf(b.z); us[7] = f2bf(b.w);
  *(uint4*)(out + i) = o;
}

// ---------------------------------------------------------------------------
// W [K][N] fp32 -> WT [N][K] bf16  (32x32 LDS tiles)
// ---------------------------------------------------------------------------
__global__ __launch_bounds__(256)
void wtrans(const float* __restrict__ W, u16* __restrict__ WT, int K, int N) {
  __shared__ float t[32][33];
  const int tx = threadIdx.x & 31, ty = threadIdx.x >> 5;   // 32 x 8
  const int n0 = blockIdx.x * 32, k0 = blockIdx.y * 32;
#pragma unroll
  for (int r = 0; r < 32; r += 8)
    t[ty + r][tx] = W[(long)(k0 + ty + r) * N + n0 + tx];
  __syncthreads();
#pragma unroll
  for (int r = 0; r < 32; r += 8)
    WT[(long)(n0 + ty + r) * K + k0 + tx] = f2bf(t[tx][ty + r]);
}

// ---------------------------------------------------------------------------
extern "C" void kernel_launch(void* const* d_in, const int* in_sizes, int n_in,
                              void* d_out, int out_size, void* d_ws, size_t ws_size,
                              hipStream_t stream) {
  const float* x  = (const float*)d_in[0];
  const float* W1 = (const float*)d_in[1];
  const float* b1 = (const float*)d_in[2];
  const float* Wq = (const float*)d_in[3];
  const float* bq = (const float*)d_in[4];
  const float* Wk = (const float*)d_in[5];
  const float* bk = (const float*)d_in[6];
  const float* Wv = (const float*)d_in[7];
  const float* bv = (const float*)d_in[8];
  const float* W2 = (const float*)d_in[9];
  const float* b2 = (const float*)d_in[10];
  const float* Wsm = (const float*)d_in[11];
  const float* bs = (const float*)d_in[12];
  float* out = (float*)d_out;

  const long M   = (long)BB * SS;        // 16384
  const long MD  = M * DHID;             // 16.77M
  const long SD  = (long)SS * DHID;      // per-batch stride
  const long SSq = (long)SS * SS;        // per-batch score elems
  const long NX  = M * DIN;              // x elems

  // workspace layout (u16 elements):
  u16* wsb = (u16*)d_ws;
  u16* xb  = wsb;                        // [M][768]
  u16* W1T = xb  + NX;                   // [1024][768]
  u16* WqT = W1T + (long)DHID * DIN;     // [1024][1024]
  u16* WkT = WqT + (long)DHID * DHID;
  u16* WvT = WkT + (long)DHID * DHID;
  u16* W2T = WvT + (long)DHID * DHID;
  u16* WsT = W2T + (long)DHID * DHID;    // [1024][768]
  u16* h   = WsT + (long)DHID * DIN;     // [M][1024] bf16
  u16* q   = h + MD;
  u16* k   = q + MD;
  u16* scores = k + MD;                  // chunked
  u16* vT  = (u16*)d_out;                // [B][1024][2048] bf16, dead before final GEMM

  long avail = (long)(ws_size / 2) - (scores - wsb);
  int nb = (int)(avail / SSq);
  if (nb > BB) nb = BB;
  if (nb < 1) nb = 1;

  // --- convert inputs to bf16 (and transpose weights) ---
  cvt8<<<(unsigned)((NX / 8 + 255) / 256), 256, 0, stream>>>(x, xb, NX);
  wtrans<<<dim3(DHID / 32, DIN / 32), 256, 0, stream>>>(W1, W1T, DIN, DHID);
  wtrans<<<dim3(DHID / 32, DHID / 32), 256, 0, stream>>>(Wq, WqT, DHID, DHID);
  wtrans<<<dim3(DHID / 32, DHID / 32), 256, 0, stream>>>(Wk, WkT, DHID, DHID);
  wtrans<<<dim3(DHID / 32, DHID / 32), 256, 0, stream>>>(Wv, WvT, DHID, DHID);
  wtrans<<<dim3(DHID / 32, DHID / 32), 256, 0, stream>>>(W2, W2T, DHID, DHID);
  wtrans<<<dim3(DHID / 32, DIN / 32), 256, 0, stream>>>(Wsm, WsT, DIN, DHID);

  const dim3 gMain(DHID / 256, M / 256, 1);   // (4,64) = 256 blocks

  // 1) h = relu(x @ W1 + b1)
  gemm256<0, true, false><<<gMain, 512, 0, stream>>>(
      xb, W1T, b1, nullptr, h, (int)M, DHID, DIN, 1.f, 0, 0, 0);
  // 2) q,k (bf16), v (transposed per batch)
  gemm256<0, false, false><<<gMain, 512, 0, stream>>>(
      h, WqT, bq, nullptr, q, (int)M, DHID, DHID, 1.f, 0, 0, 0);
  gemm256<0, false, false><<<gMain, 512, 0, stream>>>(
      h, WkT, bk, nullptr, k, (int)M, DHID, DHID, 1.f, 0, 0, 0);
  gemm256<1, false, false><<<gMain, 512, 0, stream>>>(
      h, WvT, bv, nullptr, vT, (int)M, DHID, DHID, 1.f, 0, 0, 0);

  // 3-5) attention, chunked over batches to fit scores in ws
  const float scale = 0.03125f;  // 1/sqrt(1024)
  for (int b0 = 0; b0 < BB; b0 += nb) {
    const int cb = (b0 + nb <= BB) ? nb : (BB - b0);
    gemm256<0, false, false><<<dim3(SS / 256, SS / 256, cb), 512, 0, stream>>>(
        q + (long)b0 * SD, k + (long)b0 * SD, nullptr, nullptr, scores,
        SS, SS, DHID, scale, SD, SD, SSq);
    softmax2048b<<<cb * SS, 256, 0, stream>>>(scores);
    gemm256<0, false, false><<<dim3(DHID / 256, SS / 256, cb), 512, 0, stream>>>(
        scores, vT + (long)b0 * SD, nullptr, nullptr, h + (long)b0 * SD,
        SS, DHID, SS, 1.f, SSq, SD, SD);
  }

  // 6) r = x @ Ws + bs + attn_out   (attn_out bf16 in h; r -> q region)
  gemm256<0, false, true><<<gMain, 512, 0, stream>>>(
      xb, WsT, bs, h, q, (int)M, DHID, DIN, 1.f, 0, 0, 0);

  // 7) out = relu(r @ W2 + b2) -> fp32 d_out (vT region dead by now)
  gemm256<2, true, false><<<gMain, 512, 0, stream>>>(
      q, W2T, b2, nullptr, out, (int)M, DHID, DHID, 1.f, 0, 0, 0);
}